// Round 1
// baseline (345.391 us; speedup 1.0000x reference)
//
#include <hip/hip_runtime.h>
#include <hip/hip_bf16.h>
#include <cstdint>

// ---------------------------------------------------------------------------
// WindowAttention: B windows (2048), N=64 tokens, DIM=192, H=6 heads, d=32.
// Pipeline: prep (weights -> bf16 MFMA-fragment-linear layout, comb = bias+mask)
//           qkv  (per-window MFMA GEMM, barrier-free K-loop, B-frags from L2)
//           attn (per (window,head): QK^T, softmax in regs, PV)
//           proj (per-window MFMA GEMM, barrier-free K-loop)
// All matmuls: v_mfma_f32_16x16x32_bf16, fp32 accumulate. Softmax fp32.
// V is stored transposed ([B,H,d,N]) so qkv can vector-store it and attn can
// stage it with straight uint4 copies.
// ---------------------------------------------------------------------------

#define NTOK 64
#define NH 6
#define HD 32
#define WDIM 192
#define SCALE 0.17677669529663689f

typedef __bf16 bf16x8 __attribute__((ext_vector_type(8)));
typedef float f32x4 __attribute__((ext_vector_type(4)));

__device__ inline unsigned short f2bf(float f) {
    union { float f; unsigned u; } v; v.f = f;
    unsigned r = v.u + 0x7fff + ((v.u >> 16) & 1);   // RNE
    return (unsigned short)(r >> 16);
}

// ---------------------------------------------------------------------------
// K0: weight cast into MFMA B-fragment-linear order + combined bias table.
// Fragment layout: for 16x16x32 bf16 MFMA, lane (quad=lane>>4, l15=lane&15)
// wants B[n][k] with n = ntile*16 + l15, k = ks*32 + quad*8 + j (j=0..7).
// We store Wfrag[((ntile*6 + ks)*64 + lane)*8 + j] so a wave's fragment load
// is one fully-coalesced 1 KB read (global_load_dwordx4 per lane), L2-hot.
// comb[w][h][r][c] = rpbt[relidx(r,c)][h] + mask[w][r][c]  (64*6*64*64 fp32)
// ---------------------------------------------------------------------------
__global__ __launch_bounds__(256) void prep_kernel(
    const float* __restrict__ w_qkv, const float* __restrict__ w_proj,
    const float* __restrict__ rpbt, const float* __restrict__ mask,
    unsigned short* __restrict__ wqkv_f, unsigned short* __restrict__ wproj_f,
    float* __restrict__ comb) {
    int idx = blockIdx.x * 256 + threadIdx.x;
    if (idx < 576 * 192) {
        int j = idx & 7, lane = (idx >> 3) & 63, t = idx >> 9;   // t = 0..215
        int ks = t % 6, ntile = t / 6;                           // ntile 0..35
        int n = ntile * 16 + (lane & 15);                        // 0..575
        int k = ks * 32 + (lane >> 4) * 8 + j;                   // 0..191
        wqkv_f[idx] = f2bf(w_qkv[k * 576 + n]);
        return;
    }
    int i2 = idx - 576 * 192;
    if (i2 < 192 * 192) {
        int j = i2 & 7, lane = (i2 >> 3) & 63, t = i2 >> 9;      // t = 0..71
        int ks = t % 6, ntile = t / 6;                           // ntile 0..11
        int n = ntile * 16 + (lane & 15);                        // 0..191
        int k = ks * 32 + (lane >> 4) * 8 + j;                   // 0..191
        wproj_f[i2] = f2bf(w_proj[k * 192 + n]);
        return;
    }
    int i3 = i2 - 192 * 192;
    if (i3 < 64 * NH * NTOK * NTOK) {
        int c = i3 & 63, r = (i3 >> 6) & 63;
        int h = (i3 >> 12) % NH;
        int w = i3 / (NH * 4096);
        int rr = (r >> 3) - (c >> 3) + 7;     // row-coord delta (0..14)
        int cc = (r & 7) - (c & 7) + 7;       // col-coord delta (0..14)
        comb[i3] = rpbt[(rr * 15 + cc) * NH + h] + mask[w * 4096 + r * 64 + c];
    }
}

// ---------------------------------------------------------------------------
// K1: qkv projection. One block per window. X(64x192 fp32) -> LDS bf16 once
// (single barrier). Then a barrier-free K-loop: B-fragments stream from
// global (fragment-linear, L2-resident), A-fragments from LDS, 12 MFMA/step.
// Wave w covers cols [48w,48w+48) of each 192-col chunk (Q,K,V).
// Q,K stored (B,H,N,d); V stored transposed (B,H,d,N) with 8B vector stores.
// ---------------------------------------------------------------------------
__global__ __launch_bounds__(256) void qkv_kernel(
    const float* __restrict__ X, const unsigned short* __restrict__ Wf,
    const float* __restrict__ b_qkv,
    unsigned short* __restrict__ Qw, unsigned short* __restrict__ Kw,
    unsigned short* __restrict__ Vw) {
    __shared__ unsigned short lx[64 * 200];
    const int tid = threadIdx.x;
    const int bwin = blockIdx.x;

    // stage X tile (64x192 fp32) as bf16
    const float4* xg = (const float4*)(X + (size_t)bwin * 64 * 192);
    for (int i = 0; i < 12; i++) {
        int e4 = tid + i * 256;            // 3072 float4
        int row = e4 / 48, c4 = e4 % 48;
        float4 v = xg[row * 48 + c4];
        union { unsigned short s[4]; uint2 u; } pk;
        pk.s[0] = f2bf(v.x); pk.s[1] = f2bf(v.y);
        pk.s[2] = f2bf(v.z); pk.s[3] = f2bf(v.w);
        *(uint2*)&lx[row * 200 + c4 * 4] = pk.u;
    }
    __syncthreads();

    const int wave = tid >> 6, lane = tid & 63;
    const int l15 = lane & 15, quad = lane >> 4;

    for (int chunk = 0; chunk < 3; chunk++) {
        f32x4 acc[4][3];
        for (int mt = 0; mt < 4; mt++)
            for (int nt = 0; nt < 3; nt++)
                acc[mt][nt] = (f32x4){0.f, 0.f, 0.f, 0.f};

        // wave's first n-tile within the global 576-col space
        const unsigned short* wbase =
            Wf + ((size_t)(chunk * 12 + wave * 3) * 6) * 512 + lane * 8;

        for (int ks = 0; ks < 6; ks++) {
            bf16x8 bfr[3];
            for (int nt = 0; nt < 3; nt++)
                bfr[nt] = *(const bf16x8*)&wbase[(nt * 6 + ks) * 512];
            bf16x8 af[4];
            for (int mt = 0; mt < 4; mt++)
                af[mt] = *(const bf16x8*)&lx[(mt * 16 + l15) * 200 + ks * 32 + quad * 8];
            for (int mt = 0; mt < 4; mt++)
                for (int nt = 0; nt < 3; nt++)
                    acc[mt][nt] = __builtin_amdgcn_mfma_f32_16x16x32_bf16(
                        af[mt], bfr[nt], acc[mt][nt], 0, 0, 0);
        }

        // epilogue: C/D layout col=lane&15, row=(lane>>4)*4+reg
        if (chunk < 2) {
            unsigned short* dst = (chunk == 0) ? Qw : Kw;
            for (int nt = 0; nt < 3; nt++) {
                int cw = wave * 48 + nt * 16 + l15;        // 0..191 within chunk
                float bias = b_qkv[chunk * 192 + cw];
                int h = cw >> 5, d = cw & 31;
                size_t base = ((size_t)(bwin * NH + h)) * NTOK * HD + d;
                for (int mt = 0; mt < 4; mt++)
                    for (int r = 0; r < 4; r++) {
                        int t = mt * 16 + quad * 4 + r;
                        dst[base + (size_t)t * HD] = f2bf(acc[mt][nt][r] + bias);
                    }
            }
        } else {
            // V transposed: [bwh][d][token], 4 consecutive tokens per lane
            for (int nt = 0; nt < 3; nt++) {
                int cw = wave * 48 + nt * 16 + l15;
                float bias = b_qkv[2 * 192 + cw];
                int h = cw >> 5, d = cw & 31;
                size_t base = ((size_t)(bwin * NH + h)) * NTOK * HD + (size_t)d * NTOK;
                for (int mt = 0; mt < 4; mt++) {
                    union { unsigned short s[4]; uint2 u; } pk;
                    for (int r = 0; r < 4; r++)
                        pk.s[r] = f2bf(acc[mt][nt][r] + bias);
                    *(uint2*)&Vw[base + mt * 16 + quad * 4] = pk.u;
                }
            }
        }
    }
}

// ---------------------------------------------------------------------------
// K2: attention. One block per (window, head). 4 waves; wave w owns query
// rows [16w,16w+16). S=QK^T (4 MFMA/wave), softmax in registers via 16-lane
// shfl_xor (row = quad*4+reg lives in a 16-consecutive-lane group), P->LDS
// bf16, PV (4 MFMA/wave), normalize by row-sum, write x_att bf16 (B,N,192).
// V arrives already transposed ([d][token]) -> straight uint4 staging.
// ---------------------------------------------------------------------------
__global__ __launch_bounds__(256) void attn_kernel(
    const unsigned short* __restrict__ Qw, const unsigned short* __restrict__ Kw,
    const unsigned short* __restrict__ Vw, const float* __restrict__ comb,
    unsigned short* __restrict__ xatt) {
    __shared__ unsigned short lq[64 * 40];
    __shared__ unsigned short lk[64 * 40];
    __shared__ unsigned short lvt[32 * 72];    // V transposed [d][token]
    __shared__ unsigned short lsp[64 * 72];    // P bf16 [row][key]
    __shared__ float lcomb[4096];

    const int tid = threadIdx.x;
    const int bwh = blockIdx.x;           // bwin*6 + h
    const int bwin = bwh / NH, h = bwh % NH;

    // stage Q, K, V
    {
        int e = tid * 8;                   // 2048 bf16 each
        int t = e >> 5, d = e & 31;
        const unsigned short* qg = Qw + (size_t)bwh * 2048;
        const unsigned short* kg = Kw + (size_t)bwh * 2048;
        const unsigned short* vg = Vw + (size_t)bwh * 2048;
        *(uint4*)&lq[t * 40 + d] = *(const uint4*)&qg[e];
        *(uint4*)&lk[t * 40 + d] = *(const uint4*)&kg[e];
        int vd = tid >> 3, vt = (tid & 7) * 8;   // V already [d][t]
        *(uint4*)&lvt[vd * 72 + vt] = *(const uint4*)&vg[e];
    }
    // stage comb (bias+mask) slice: 4096 fp32
    {
        const float4* cg = (const float4*)(comb + ((size_t)(bwin & 63) * NH + h) * 4096);
        for (int i = 0; i < 4; i++)
            ((float4*)lcomb)[tid + i * 256] = cg[tid + i * 256];
    }
    __syncthreads();

    const int wave = tid >> 6, lane = tid & 63;
    const int l15 = lane & 15, quad = lane >> 4;
    const int mbase = wave * 16;

    // S = Q K^T  (K=32, one MFMA per n-tile)
    bf16x8 aq = *(const bf16x8*)&lq[(mbase + l15) * 40 + quad * 8];
    f32x4 sacc[4];
    for (int j = 0; j < 4; j++) {
        bf16x8 bk = *(const bf16x8*)&lk[(j * 16 + l15) * 40 + quad * 8];
        f32x4 z = (f32x4){0.f, 0.f, 0.f, 0.f};
        sacc[j] = __builtin_amdgcn_mfma_f32_16x16x32_bf16(aq, bk, z, 0, 0, 0);
    }

    // softmax (fp32, registers). s[j][r]: row = mbase+quad*4+r, col = j*16+l15
    float s[4][4];
    for (int j = 0; j < 4; j++)
        for (int r = 0; r < 4; r++)
            s[j][r] = sacc[j][r] * SCALE + lcomb[(mbase + quad * 4 + r) * 64 + j * 16 + l15];
    float p[4][4], rsum[4];
    for (int r = 0; r < 4; r++) {
        float m = fmaxf(fmaxf(s[0][r], s[1][r]), fmaxf(s[2][r], s[3][r]));
        for (int o = 1; o < 16; o <<= 1) m = fmaxf(m, __shfl_xor(m, o, 64));
        for (int j = 0; j < 4; j++) p[j][r] = __expf(s[j][r] - m);
        float su = p[0][r] + p[1][r] + p[2][r] + p[3][r];
        for (int o = 1; o < 16; o <<= 1) su += __shfl_xor(su, o, 64);
        rsum[r] = su;
    }
    // P (unnormalized) -> LDS bf16 in A-operand layout [row][key]
    for (int j = 0; j < 4; j++)
        for (int r = 0; r < 4; r++)
            lsp[(mbase + quad * 4 + r) * 72 + j * 16 + l15] = f2bf(p[j][r]);
    __syncthreads();

    // O = P V   (K=64 -> 2 k-steps, 2 n-tiles of d)
    f32x4 oacc[2];
    oacc[0] = (f32x4){0.f, 0.f, 0.f, 0.f};
    oacc[1] = (f32x4){0.f, 0.f, 0.f, 0.f};
    for (int kstep = 0; kstep < 2; kstep++) {
        bf16x8 ap = *(const bf16x8*)&lsp[(mbase + l15) * 72 + kstep * 32 + quad * 8];
        for (int n2 = 0; n2 < 2; n2++) {
            bf16x8 bv = *(const bf16x8*)&lvt[(n2 * 16 + l15) * 72 + kstep * 32 + quad * 8];
            oacc[n2] = __builtin_amdgcn_mfma_f32_16x16x32_bf16(ap, bv, oacc[n2], 0, 0, 0);
        }
    }
    // normalize + store: rsum[r] matches row = mbase+quad*4+r exactly
    unsigned short* og = xatt + (size_t)bwin * NTOK * WDIM + h * HD;
    for (int r = 0; r < 4; r++) {
        float inv = 1.0f / rsum[r];
        int t = mbase + quad * 4 + r;
        for (int n2 = 0; n2 < 2; n2++)
            og[(size_t)t * WDIM + n2 * 16 + l15] = f2bf(oacc[n2][r] * inv);
    }
}

// ---------------------------------------------------------------------------
// K3: output projection. One block per window. x_att tile (bf16) -> LDS once,
// then barrier-free K-loop with B-fragments streamed from global (L2-hot).
// fp32 output + bias.
// ---------------------------------------------------------------------------
__global__ __launch_bounds__(256) void proj_kernel(
    const unsigned short* __restrict__ Xa, const unsigned short* __restrict__ Wf,
    const float* __restrict__ b_proj, float* __restrict__ out) {
    __shared__ unsigned short lx[64 * 200];
    const int tid = threadIdx.x;
    const int bwin = blockIdx.x;

    const unsigned short* xg = Xa + (size_t)bwin * 64 * 192;
    for (int i = 0; i < 6; i++) {
        int e8 = tid + i * 256;            // 1536 chunks of 8 bf16
        int row = e8 / 24, c8 = e8 % 24;
        *(uint4*)&lx[row * 200 + c8 * 8] = *(const uint4*)&xg[row * 192 + c8 * 8];
    }
    __syncthreads();

    const int wave = tid >> 6, lane = tid & 63;
    const int l15 = lane & 15, quad = lane >> 4;

    f32x4 acc[4][3];
    for (int mt = 0; mt < 4; mt++)
        for (int nt = 0; nt < 3; nt++)
            acc[mt][nt] = (f32x4){0.f, 0.f, 0.f, 0.f};

    const unsigned short* wbase = Wf + ((size_t)(wave * 3) * 6) * 512 + lane * 8;

    for (int ks = 0; ks < 6; ks++) {
        bf16x8 bfr[3];
        for (int nt = 0; nt < 3; nt++)
            bfr[nt] = *(const bf16x8*)&wbase[(nt * 6 + ks) * 512];
        bf16x8 af[4];
        for (int mt = 0; mt < 4; mt++)
            af[mt] = *(const bf16x8*)&lx[(mt * 16 + l15) * 200 + ks * 32 + quad * 8];
        for (int mt = 0; mt < 4; mt++)
            for (int nt = 0; nt < 3; nt++)
                acc[mt][nt] = __builtin_amdgcn_mfma_f32_16x16x32_bf16(
                    af[mt], bfr[nt], acc[mt][nt], 0, 0, 0);
    }

    for (int nt = 0; nt < 3; nt++) {
        int cw = wave * 48 + nt * 16 + l15;       // 0..191
        float bias = b_proj[cw];
        for (int mt = 0; mt < 4; mt++)
            for (int r = 0; r < 4; r++) {
                int t = mt * 16 + quad * 4 + r;
                out[((size_t)bwin * 64 + t) * 192 + cw] = acc[mt][nt][r] + bias;
            }
    }
}

// ---------------------------------------------------------------------------
extern "C" void kernel_launch(void* const* d_in, const int* in_sizes, int n_in,
                              void* d_out, int out_size, void* d_ws, size_t ws_size,
                              hipStream_t stream) {
    const float* x      = (const float*)d_in[0];
    const float* mask   = (const float*)d_in[1];
    const float* w_qkv  = (const float*)d_in[2];
    const float* b_qkv  = (const float*)d_in[3];
    const float* rpbt   = (const float*)d_in[4];
    const float* w_proj = (const float*)d_in[5];
    const float* b_proj = (const float*)d_in[6];
    float* out = (float*)d_out;

    const int B = in_sizes[0] / (NTOK * WDIM);   // 2048

    char* ws = (char*)d_ws;
    size_t o = 0;
    unsigned short* Qw = (unsigned short*)(ws + o); o += (size_t)B * NH * NTOK * HD * 2;
    unsigned short* Kw = (unsigned short*)(ws + o); o += (size_t)B * NH * NTOK * HD * 2;
    unsigned short* Vw = (unsigned short*)(ws + o); o += (size_t)B * NH * NTOK * HD * 2;
    unsigned short* Xa = (unsigned short*)(ws + o); o += (size_t)B * NTOK * WDIM * 2;
    unsigned short* Wq = (unsigned short*)(ws + o); o += 576 * 192 * 2;
    unsigned short* Wp = (unsigned short*)(ws + o); o += 192 * 192 * 2;
    float* comb        = (float*)(ws + o);         o += (size_t)64 * NH * NTOK * NTOK * 4;

    const int prep_elems = 576 * 192 + 192 * 192 + 64 * NH * NTOK * NTOK;
    prep_kernel<<<(prep_elems + 255) / 256, 256, 0, stream>>>(
        w_qkv, w_proj, rpbt, mask, Wq, Wp, comb);
    qkv_kernel<<<B, 256, 0, stream>>>(x, Wq, b_qkv, Qw, Kw, Vw);
    attn_kernel<<<B * NH, 256, 0, stream>>>(Qw, Kw, Vw, comb, Xa);
    proj_kernel<<<B, 256, 0, stream>>>(Xa, Wp, b_proj, out);
}

// Round 3
// 300.604 us; speedup vs baseline: 1.1490x; 1.1490x over previous
//
#include <hip/hip_runtime.h>
#include <hip/hip_bf16.h>
#include <cstdint>

// ---------------------------------------------------------------------------
// WindowAttention, fully fused, static-LDS (<=64KB): B windows (2048), N=64,
// DIM=192, H=6 heads, d=32.
//   prep : weights -> bf16 MFMA-fragment-linear, comb = rel_bias + mask
//   fused: per-window block (512 thr, 8 waves). 3 passes over head-pairs:
//            pass p: QKV GEMM (A-frags in regs, B-frags from L2) for heads
//            {2p,2p+1} -> Q,K,V^T in LDS -> attention (1 task/wave, softmax
//            in regs, P transposed via LDS scratch aliasing the dead X tile)
//            -> Xa slice in LDS -> rank-64 proj update into register acc.
//          After 3 passes: write out fp32 + bias.
// Q/K/V/Xa never touch HBM: ideal traffic = X in (100MB) + out (100MB).
// No dynamic LDS, no hipFuncSetAttribute (graph-capture-safe).
// ---------------------------------------------------------------------------

#define NTOK 64
#define NH 6
#define HD 32
#define WDIM 192
#define SCALE 0.17677669529663689f

typedef __bf16 bf16x8 __attribute__((ext_vector_type(8)));
typedef float f32x4 __attribute__((ext_vector_type(4)));

__device__ inline unsigned short f2bf(float f) {
    union { float f; unsigned u; } v; v.f = f;
    unsigned r = v.u + 0x7fff + ((v.u >> 16) & 1);   // RNE
    return (unsigned short)(r >> 16);
}

// ---------------------------------------------------------------------------
// K0: weight cast into MFMA B-fragment-linear order + combined bias table.
// Wfrag[((ntile*6 + ks)*64 + lane)*8 + j] = W[k][n], n = ntile*16+(lane&15),
// k = ks*32+(lane>>4)*8+j  -> a wave's B-fragment is one coalesced 1KB read.
// comb[w][h][r][c] = rpbt[relidx(r,c)][h] + mask[w][r][c]  (64*6*64*64 fp32)
// ---------------------------------------------------------------------------
__global__ __launch_bounds__(256) void prep_kernel(
    const float* __restrict__ w_qkv, const float* __restrict__ w_proj,
    const float* __restrict__ rpbt, const float* __restrict__ mask,
    unsigned short* __restrict__ wqkv_f, unsigned short* __restrict__ wproj_f,
    float* __restrict__ comb) {
    int idx = blockIdx.x * 256 + threadIdx.x;
    if (idx < 576 * 192) {
        int j = idx & 7, lane = (idx >> 3) & 63, t = idx >> 9;   // t = 0..215
        int ks = t % 6, ntile = t / 6;                           // ntile 0..35
        int n = ntile * 16 + (lane & 15);                        // 0..575
        int k = ks * 32 + (lane >> 4) * 8 + j;                   // 0..191
        wqkv_f[idx] = f2bf(w_qkv[k * 576 + n]);
        return;
    }
    int i2 = idx - 576 * 192;
    if (i2 < 192 * 192) {
        int j = i2 & 7, lane = (i2 >> 3) & 63, t = i2 >> 9;      // t = 0..71
        int ks = t % 6, ntile = t / 6;                           // ntile 0..11
        int n = ntile * 16 + (lane & 15);                        // 0..191
        int k = ks * 32 + (lane >> 4) * 8 + j;                   // 0..191
        wproj_f[i2] = f2bf(w_proj[k * 192 + n]);
        return;
    }
    int i3 = i2 - 192 * 192;
    if (i3 < 64 * NH * NTOK * NTOK) {
        int c = i3 & 63, r = (i3 >> 6) & 63;
        int h = (i3 >> 12) % NH;
        int w = i3 / (NH * 4096);
        int rr = (r >> 3) - (c >> 3) + 7;     // row-coord delta (0..14)
        int cc = (r & 7) - (c & 7) + 7;       // col-coord delta (0..14)
        comb[i3] = rpbt[(rr * 15 + cc) * NH + h] + mask[w * 4096 + r * 64 + c];
    }
}

// ---------------------------------------------------------------------------
// Fused per-window kernel. 512 threads = 8 waves: wm = wave>>2 (row half),
// wn = wave&3 (n-group). Static LDS (shorts, 32256 total = 64512 B):
//   lx   [64][200] 12800  X bf16; dead after af-load -> reused as per-wave
//                         P scratch lsp[8][16][72] (9216)
//   lq2  [2][64][40] 5120 Q of current head-pair (row=token, col=d)
//   lk2  [2][64][40] 5120 K
//   lvt2 [2][32][72] 4608 V^T (row=d, col=token)
//   lxa  [64][72]    4608 Xa slice of current pass (64 tokens x 64 chans)
// ---------------------------------------------------------------------------
__global__ __launch_bounds__(512, 2) void fused_kernel(
    const float* __restrict__ X, const unsigned short* __restrict__ Wqf,
    const float* __restrict__ b_qkv, const unsigned short* __restrict__ Wpf,
    const float* __restrict__ b_proj, const float* __restrict__ comb,
    float* __restrict__ out) {
    __shared__ unsigned short lx[12800];
    __shared__ unsigned short lq2[5120];
    __shared__ unsigned short lk2[5120];
    __shared__ unsigned short lvt2[4608];
    __shared__ unsigned short lxa[4608];

    const int tid = threadIdx.x;
    const int bwin = blockIdx.x;
    const int wave = tid >> 6, lane = tid & 63;
    const int l15 = lane & 15, quad = lane >> 4;
    const int wm = wave >> 2, wn = wave & 3;

    // ---- stage X (64x192 fp32 -> bf16) ----
    const float4* xg = (const float4*)(X + (size_t)bwin * 64 * 192);
    for (int i = 0; i < 6; i++) {
        int e4 = tid + i * 512;            // 3072 float4
        int row = e4 / 48, c4 = e4 % 48;
        float4 v = xg[e4];
        union { unsigned short s[4]; uint2 u; } pk;
        pk.s[0] = f2bf(v.x); pk.s[1] = f2bf(v.y);
        pk.s[2] = f2bf(v.z); pk.s[3] = f2bf(v.w);
        *(uint2*)&lx[row * 200 + c4 * 4] = pk.u;
    }
    __syncthreads();

    // ---- hoist A-fragments (X rows wm*32..+32, all K) into registers ----
    bf16x8 af[2][6];
    for (int mt = 0; mt < 2; mt++)
        for (int ks = 0; ks < 6; ks++)
            af[mt][ks] = *(const bf16x8*)&lx[(wm * 32 + mt * 16 + l15) * 200 + ks * 32 + quad * 8];
    // lx is dead from here; its space is the P scratch:
    unsigned short* lspw = lx + wave * 1152;   // [16][72] per wave

    f32x4 pacc[2][3];                           // proj accumulator, all passes
    for (int mt = 0; mt < 2; mt++)
        for (int nt = 0; nt < 3; nt++)
            pacc[mt][nt] = (f32x4){0.f, 0.f, 0.f, 0.f};

    const float* combg = comb + ((size_t)(bwin & 63) * NH) * 4096;

    for (int p = 0; p < 3; p++) {
        // ---- QKV GEMM for head-pair p: 12 ntiles (c,j), wave does 3 ----
        f32x4 acc[2][3];
        for (int mt = 0; mt < 2; mt++)
            for (int i = 0; i < 3; i++)
                acc[mt][i] = (f32x4){0.f, 0.f, 0.f, 0.f};
        for (int ks = 0; ks < 6; ks++) {
            bf16x8 bfr[3];
            for (int i = 0; i < 3; i++) {
                int f = wn * 3 + i, c = f >> 2, j = f & 3;
                bfr[i] = *(const bf16x8*)&Wqf[
                    ((size_t)((c * 12 + p * 4 + j) * 6 + ks)) * 512 + lane * 8];
            }
            for (int mt = 0; mt < 2; mt++)
                for (int i = 0; i < 3; i++)
                    acc[mt][i] = __builtin_amdgcn_mfma_f32_16x16x32_bf16(
                        af[mt][ks], bfr[i], acc[mt][i], 0, 0, 0);
        }
        // barrier: prev pass's attention/proj reads of lq2/lk2/lvt2/lxa done
        // (and, for p==0, all waves' af-loads done before lspw overlays lx)
        __syncthreads();
        // epilogue -> LDS. C/D layout: col = l15, row = quad*4 + r
        for (int i = 0; i < 3; i++) {
            int f = wn * 3 + i, c = f >> 2, j = f & 3;
            int cw = j * 16 + l15;                 // 0..63 within pass
            float bias = b_qkv[c * 192 + p * 64 + cw];
            int hl = cw >> 5, d = cw & 31;
            if (c < 2) {
                unsigned short* dst = (c == 0) ? lq2 : lk2;
                for (int mt = 0; mt < 2; mt++)
                    for (int r = 0; r < 4; r++) {
                        int t = wm * 32 + mt * 16 + quad * 4 + r;
                        dst[(hl * 64 + t) * 40 + d] = f2bf(acc[mt][i][r] + bias);
                    }
            } else {
                for (int mt = 0; mt < 2; mt++) {
                    union { unsigned short s[4]; uint2 u; } pk;
                    for (int r = 0; r < 4; r++)
                        pk.s[r] = f2bf(acc[mt][i][r] + bias);
                    int t0 = wm * 32 + mt * 16 + quad * 4;
                    *(uint2*)&lvt2[(hl * 32 + d) * 72 + t0] = pk.u;
                }
            }
        }
        __syncthreads();

        // ---- attention: 8 tasks, exactly one per wave ----
        const int hl = wm;                 // local head 0..1
        const int mbase = wn * 16;         // query row tile
        const int hg = p * 2 + hl;         // global head

        float cmb[4][4];
        for (int j = 0; j < 4; j++)
            for (int r = 0; r < 4; r++)
                cmb[j][r] = combg[hg * 4096 + (mbase + quad * 4 + r) * 64 + j * 16 + l15];

        // S = Q K^T (d=32 = one k-step)
        bf16x8 aq = *(const bf16x8*)&lq2[(hl * 64 + mbase + l15) * 40 + quad * 8];
        f32x4 sacc[4];
        for (int j = 0; j < 4; j++) {
            bf16x8 bk = *(const bf16x8*)&lk2[(hl * 64 + j * 16 + l15) * 40 + quad * 8];
            f32x4 z = (f32x4){0.f, 0.f, 0.f, 0.f};
            sacc[j] = __builtin_amdgcn_mfma_f32_16x16x32_bf16(aq, bk, z, 0, 0, 0);
        }

        // softmax in registers; a row's 64 cols live in the 16-lane l15 group
        float pr[4][4], rsum[4];
        for (int r = 0; r < 4; r++) {
            float s0 = sacc[0][r] * SCALE + cmb[0][r];
            float s1 = sacc[1][r] * SCALE + cmb[1][r];
            float s2 = sacc[2][r] * SCALE + cmb[2][r];
            float s3 = sacc[3][r] * SCALE + cmb[3][r];
            float m = fmaxf(fmaxf(s0, s1), fmaxf(s2, s3));
            for (int o = 1; o < 16; o <<= 1) m = fmaxf(m, __shfl_xor(m, o, 64));
            pr[0][r] = __expf(s0 - m); pr[1][r] = __expf(s1 - m);
            pr[2][r] = __expf(s2 - m); pr[3][r] = __expf(s3 - m);
            float su = pr[0][r] + pr[1][r] + pr[2][r] + pr[3][r];
            for (int o = 1; o < 16; o <<= 1) su += __shfl_xor(su, o, 64);
            rsum[r] = su;
        }

        // P (unnormalized) -> wave-private scratch [16][72] (same-wave RAW)
        for (int j = 0; j < 4; j++)
            for (int r = 0; r < 4; r++)
                lspw[(quad * 4 + r) * 72 + j * 16 + l15] = f2bf(pr[j][r]);

        // O = P V^T  (K=64 -> 2 k-steps, 2 d-tiles)
        f32x4 oacc[2];
        oacc[0] = (f32x4){0.f, 0.f, 0.f, 0.f};
        oacc[1] = (f32x4){0.f, 0.f, 0.f, 0.f};
        for (int kstep = 0; kstep < 2; kstep++) {
            bf16x8 ap = *(const bf16x8*)&lspw[l15 * 72 + kstep * 32 + quad * 8];
            for (int n2 = 0; n2 < 2; n2++) {
                bf16x8 bv = *(const bf16x8*)&lvt2[
                    (hl * 32 + n2 * 16 + l15) * 72 + kstep * 32 + quad * 8];
                oacc[n2] = __builtin_amdgcn_mfma_f32_16x16x32_bf16(ap, bv, oacc[n2], 0, 0, 0);
            }
        }

        // normalize + write Xa slice (bf16): col = hl*32 + d (in-pass channel)
        for (int r = 0; r < 4; r++) {
            float inv = 1.0f / rsum[r];
            int t = mbase + quad * 4 + r;
            for (int n2 = 0; n2 < 2; n2++)
                lxa[t * 72 + hl * 32 + n2 * 16 + l15] = f2bf(oacc[n2][r] * inv);
        }
        __syncthreads();

        // ---- proj partial: rank-64 update, k-slice [p*64, p*64+64) ----
        bf16x8 pf[2][2];
        for (int mt = 0; mt < 2; mt++)
            for (int kk = 0; kk < 2; kk++)
                pf[mt][kk] = *(const bf16x8*)&lxa[
                    (wm * 32 + mt * 16 + l15) * 72 + kk * 32 + quad * 8];
        for (int kk = 0; kk < 2; kk++) {
            bf16x8 bfr[3];
            for (int nt = 0; nt < 3; nt++)
                bfr[nt] = *(const bf16x8*)&Wpf[
                    ((size_t)((wn * 3 + nt) * 6 + (p * 2 + kk))) * 512 + lane * 8];
            for (int mt = 0; mt < 2; mt++)
                for (int nt = 0; nt < 3; nt++)
                    pacc[mt][nt] = __builtin_amdgcn_mfma_f32_16x16x32_bf16(
                        pf[mt][kk], bfr[nt], pacc[mt][nt], 0, 0, 0);
        }
        // next pass's pre-epilogue barrier protects lxa/lq2/lk2/lvt2 reuse
    }

    // ---- write out (fp32 + bias) ----
    for (int nt = 0; nt < 3; nt++) {
        int cw = wn * 48 + nt * 16 + l15;       // 0..191
        float bias = b_proj[cw];
        for (int mt = 0; mt < 2; mt++)
            for (int r = 0; r < 4; r++) {
                int t = wm * 32 + mt * 16 + quad * 4 + r;
                out[((size_t)bwin * 64 + t) * 192 + cw] = pacc[mt][nt][r] + bias;
            }
    }
}

// ---------------------------------------------------------------------------
extern "C" void kernel_launch(void* const* d_in, const int* in_sizes, int n_in,
                              void* d_out, int out_size, void* d_ws, size_t ws_size,
                              hipStream_t stream) {
    const float* x      = (const float*)d_in[0];
    const float* mask   = (const float*)d_in[1];
    const float* w_qkv  = (const float*)d_in[2];
    const float* b_qkv  = (const float*)d_in[3];
    const float* rpbt   = (const float*)d_in[4];
    const float* w_proj = (const float*)d_in[5];
    const float* b_proj = (const float*)d_in[6];
    float* out = (float*)d_out;

    const int B = in_sizes[0] / (NTOK * WDIM);   // 2048

    char* ws = (char*)d_ws;
    size_t o = 0;
    unsigned short* Wq = (unsigned short*)(ws + o); o += 576 * 192 * 2;
    unsigned short* Wp = (unsigned short*)(ws + o); o += 192 * 192 * 2;
    float* comb        = (float*)(ws + o);         o += (size_t)64 * NH * NTOK * NTOK * 4;

    const int prep_elems = 576 * 192 + 192 * 192 + 64 * NH * NTOK * NTOK;
    prep_kernel<<<(prep_elems + 255) / 256, 256, 0, stream>>>(
        w_qkv, w_proj, rpbt, mask, Wq, Wp, comb);
    fused_kernel<<<B, 512, 0, stream>>>(
        x, Wq, b_qkv, Wp, b_proj, comb, out);
}